// Round 1
// baseline (199.108 us; speedup 1.0000x reference)
//
#include <hip/hip_runtime.h>
#include <stdint.h>

// CycleFC 1w1a: out[b,o,h,w] = sum_c sign(x)[b,c,h,w+off(c)] * sign(W)[o,c] + bias[o]
// off(c) = (c+3)%7 - 3, zero-pad OOB. B=64, C=O=384, H=W=32.
//
// Binary-GEMM: pack signs (bit=1 iff <0) into 6 u64 words; out = bias2 - 2*popc(G^WB).
// bias2[o,w] = bias[o] + Nvalid(w) + 2*popc(WB & ~V(w)) precomputed in prep.
// Offsets periodic mod 7; 64%7==1 so mask for offset d in word j is PBASE<<((d-j) mod 7).
//
// R6: counters showed cyc_main latency-bound (VALU 31%, HBM 26%, occ 48%) —
// 12-wave blocks, 2 barriers, 2 blocks/CU couple read/transpose/popc/write
// phases. Split into cyc_pack (read-bound, writes 3MB G to ws, 1 barrier) +
// cyc_gemm (write-bound, zero LDS/barriers, 8 waves/SIMD). Fallback to the
// R5 fused kernel if ws_size < 3.3MB.

#define IN_CH 384
#define HH 32
#define WW 32
#define BB 64
#define HR 4   // fused kernel: h rows per block
#define HRA 2  // pack kernel: h rows per block

// bits k with k%7==0; Pm[t] == PBASE << t for t in [0,7)
#define PBASE 0x8102040810204081ull

constexpr uint64_t P7(int t) {
  uint64_t m = 0;
  for (int k = 0; k < 64; ++k)
    if (k % 7 == t) m |= (1ull << k);
  return m;
}
__device__ __constant__ uint64_t Pm[7] = {P7(0), P7(1), P7(2), P7(3), P7(4), P7(5), P7(6)};

// ---------------- prep: one block (1 wave) per output channel o --------------
__global__ __launch_bounds__(64) void cyc_prep(const float* __restrict__ wgt,
                                               const float* __restrict__ bias,
                                               uint64_t* __restrict__ wbg,
                                               float* __restrict__ bias2t,
                                               float* __restrict__ bias2w,
                                               int do_w) {
  const int o = blockIdx.x;
  const int lane = threadIdx.x;
  __shared__ uint64_t wb_sh[6];
#pragma unroll
  for (int j = 0; j < 6; ++j) {
    uint64_t m = __ballot(wgt[o * IN_CH + j * 64 + lane] < 0.0f);
    if (lane == 0) wb_sh[j] = m;
  }
  __syncthreads();
  if (lane < 6) wbg[o * 6 + lane] = wb_sh[lane];
  if (lane < WW) {
    const int w = lane;
    int nv = 0, corr = 0;
#pragma unroll
    for (int j = 0; j < 6; ++j) {
      uint64_t V = 0;
#pragma unroll
      for (int d = -3; d <= 3; ++d) {
        int wd = w + d;
        if (wd >= 0 && wd < WW) V |= Pm[(d - j + 14) % 7];
      }
      nv += __popcll(V);
      corr += __popcll(wb_sh[j] & ~V);
    }
    float val = bias[o] + (float)nv + 2.0f * (float)corr;
    // fused path layout: [w][o] (contiguous per-lane float4 in phase 2)
    bias2t[w * IN_CH + o] = val;
    // split path layout: [o][w] (per-iter 128B broadcast row)
    if (do_w) bias2w[o * WW + w] = val;
  }
}

// ---------------- split kernel 1: pack + shift, x -> G (3MB) -----------------
// block = (b, 2 h-rows), 384 threads = 6 waves, grid = 64*16 = 1024.
__global__ __launch_bounds__(384) void cyc_pack(const float* __restrict__ x,
                                                uint64_t* __restrict__ Gg) {
  __shared__ uint64_t sh_X[HRA][WW][6];  // 3072 B
  const int t = threadIdx.x;
  const int b = blockIdx.x >> 4;
  const int h0 = (blockIdx.x & 15) * HRA;
  const int wave = t >> 6, lane = t & 63;

  // phase 1: wave j packs rows r=0..1 for channels c=j*64+lane.
  const int j = wave;
  const int c = j * 64 + lane;
#pragma unroll
  for (int r = 0; r < HRA; ++r) {
    const float4* xp = reinterpret_cast<const float4*>(
        x + (size_t)((b * IN_CH + c) * HH + h0 + r) * WW);
    unsigned myw = 0;
#pragma unroll
    for (int i = 0; i < 8; ++i) {
      float4 v = xp[i];
      myw |= (v.x < 0.0f ? 1u : 0u) << (i * 4 + 0);
      myw |= (v.y < 0.0f ? 1u : 0u) << (i * 4 + 1);
      myw |= (v.z < 0.0f ? 1u : 0u) << (i * 4 + 2);
      myw |= (v.w < 0.0f ? 1u : 0u) << (i * 4 + 3);
    }
#pragma unroll
    for (int w = 0; w < WW; ++w) {
      uint64_t m = __ballot((myw >> w) & 1u);
      if (lane == 0) sh_X[r][w][j] = m;
    }
  }
  __syncthreads();

  // phase 2: G[r][w][j2] = OR_d (X[r][w+d][j2] & (PBASE << ((d-j2) mod 7)))
  // 384 tasks == 384 threads. Store layout [b][h][j][w]: wave covers 512B.
  const int r = t / 192;
  const int q = t % 192;
  const int w = q & 31, j2 = q >> 5;
  uint64_t g = 0;
#pragma unroll
  for (int d = -3; d <= 3; ++d) {
    int wd = w + d;
    if (wd >= 0 && wd < WW) g |= sh_X[r][wd][j2] & (PBASE << ((d - j2 + 14) % 7));
  }
  Gg[((size_t)(b * HH + h0 + r) * 6 + j2) * WW + w] = g;
}

// ---------------- split kernel 2: binary GEMM, G -> out ----------------------
// block = 256 threads = 4 waves, no LDS, no barriers. grid = 64*16*2 = 2048.
// bid -> (b, h-pair, o-half); lane = (r2, w); wave owns 48 output channels.
__global__ __launch_bounds__(256) void cyc_gemm(const uint64_t* __restrict__ Gg,
                                                const uint64_t* __restrict__ wbg,
                                                const float* __restrict__ bias2w,
                                                float* __restrict__ out) {
  const int t = threadIdx.x;
  const int wave = t >> 6, lane = t & 63;
  const int bid = blockIdx.x;
  const int oh = bid & 1;
  const int hp = (bid >> 1) & 15;
  const int b = bid >> 5;
  const int h0 = hp * 2;
  const int w = lane & 31, r2 = lane >> 5;
  const int h = h0 + r2;

  uint64_t g[6];
  const uint64_t* gp = Gg + (size_t)(b * HH + h) * 6 * WW + w;
#pragma unroll
  for (int j = 0; j < 6; ++j) g[j] = gp[j * WW];

  const int obase = oh * 192 + __builtin_amdgcn_readfirstlane(wave) * 48;
  const uint64_t* wp = wbg + (size_t)obase * 6;
  const float* bp = bias2w + obase * WW + w;
  // lanes cover (h0+r2)*32+w = h0*32+lane -> 256B contiguous store per o
  float* op = out + ((size_t)b * IN_CH + obase) * (HH * WW) + h0 * WW + lane;
#pragma unroll
  for (int i = 0; i < 48; ++i) {
    const uint64_t w0 = wp[i * 6 + 0], w1 = wp[i * 6 + 1], w2 = wp[i * 6 + 2];
    const uint64_t w3 = wp[i * 6 + 3], w4 = wp[i * 6 + 4], w5 = wp[i * 6 + 5];
    int mm = __popcll(g[0] ^ w0) + __popcll(g[1] ^ w1) + __popcll(g[2] ^ w2) +
             __popcll(g[3] ^ w3) + __popcll(g[4] ^ w4) + __popcll(g[5] ^ w5);
    op[i * (HH * WW)] = bp[i * WW] - 2.0f * (float)mm;
  }
}

// ---------------- fallback fused kernel (R5, 72us) ---------------------------
__global__ __launch_bounds__(768) void cyc_main(const float* __restrict__ x,
                                                const uint64_t* __restrict__ wbg,
                                                const float* __restrict__ bias2t,
                                                float* __restrict__ out) {
  __shared__ uint64_t sh_X[HR][WW][6];  // 6144 B
  __shared__ uint64_t sh_G[HR][WW][6];  // 6144 B
  const int t = threadIdx.x;
  const int b = blockIdx.x >> 3;
  const int h0 = (blockIdx.x & 7) * HR;
  const int wave = t >> 6, lane = t & 63;

#pragma unroll
  for (int p = 0; p < 2; ++p) {
    const int tau = wave + p * 12;
    const int r = tau / 6, j = tau % 6;
    const int c = j * 64 + lane;
    const float4* xp = reinterpret_cast<const float4*>(
        x + (size_t)((b * IN_CH + c) * HH + h0 + r) * WW);
    unsigned myw = 0;
#pragma unroll
    for (int i = 0; i < 8; ++i) {
      float4 v = xp[i];
      myw |= (v.x < 0.0f ? 1u : 0u) << (i * 4 + 0);
      myw |= (v.y < 0.0f ? 1u : 0u) << (i * 4 + 1);
      myw |= (v.z < 0.0f ? 1u : 0u) << (i * 4 + 2);
      myw |= (v.w < 0.0f ? 1u : 0u) << (i * 4 + 3);
    }
#pragma unroll
    for (int w = 0; w < WW; ++w) {
      uint64_t m = __ballot((myw >> w) & 1u);
      if (lane == 0) sh_X[r][w][j] = m;
    }
  }
  __syncthreads();

  {
    const int r = t / (WW * 6);
    const int q = t % (WW * 6);
    const int w = q & 31, j = q >> 5;
    uint64_t g = 0;
#pragma unroll
    for (int d = -3; d <= 3; ++d) {
      int wd = w + d;
      if (wd >= 0 && wd < WW) g |= sh_X[r][wd][j] & Pm[(d - j + 14) % 7];
    }
    sh_G[r][w][j] = g;
  }
  __syncthreads();

  const int og = __builtin_amdgcn_readfirstlane(wave);
  const int w = lane & 31, r2 = lane >> 5;
  uint64_t gA[6], gB[6];
  {
    const ulonglong2* gv = reinterpret_cast<const ulonglong2*>(&sh_G[r2][w][0]);
    ulonglong2 a0 = gv[0], a1 = gv[1], a2 = gv[2];
    gA[0] = a0.x; gA[1] = a0.y; gA[2] = a1.x; gA[3] = a1.y; gA[4] = a2.x; gA[5] = a2.y;
    const ulonglong2* hv = reinterpret_cast<const ulonglong2*>(&sh_G[2 + r2][w][0]);
    ulonglong2 b0 = hv[0], b1 = hv[1], b2 = hv[2];
    gB[0] = b0.x; gB[1] = b0.y; gB[2] = b1.x; gB[3] = b1.y; gB[4] = b2.x; gB[5] = b2.y;
  }
  float bb[32];
  {
    const float4* bsrc =
        reinterpret_cast<const float4*>(bias2t + w * IN_CH + og * 32);
    float4* bdst = reinterpret_cast<float4*>(bb);
#pragma unroll
    for (int i = 0; i < 8; ++i) bdst[i] = bsrc[i];
  }
  float* opA = out + ((size_t)b * IN_CH + og * 32) * (HH * WW) + h0 * WW + lane;
  float* opB = opA + 2 * WW;
  const uint64_t* wp = wbg + og * 32 * 6;
#pragma unroll
  for (int i = 0; i < 32; ++i) {
    const uint64_t w0 = wp[i * 6 + 0], w1 = wp[i * 6 + 1], w2 = wp[i * 6 + 2];
    const uint64_t w3 = wp[i * 6 + 3], w4 = wp[i * 6 + 4], w5 = wp[i * 6 + 5];
    int mmA = __popcll(gA[0] ^ w0) + __popcll(gA[1] ^ w1) + __popcll(gA[2] ^ w2) +
              __popcll(gA[3] ^ w3) + __popcll(gA[4] ^ w4) + __popcll(gA[5] ^ w5);
    int mmB = __popcll(gB[0] ^ w0) + __popcll(gB[1] ^ w1) + __popcll(gB[2] ^ w2) +
              __popcll(gB[3] ^ w3) + __popcll(gB[4] ^ w4) + __popcll(gB[5] ^ w5);
    opA[i * (HH * WW)] = bb[i] - 2.0f * (float)mmA;
    opB[i * (HH * WW)] = bb[i] - 2.0f * (float)mmB;
  }
}

extern "C" void kernel_launch(void* const* d_in, const int* in_sizes, int n_in,
                              void* d_out, int out_size, void* d_ws, size_t ws_size,
                              hipStream_t stream) {
  const float* x = (const float*)d_in[0];
  const float* wgt = (const float*)d_in[1];
  const float* bias = (const float*)d_in[2];
  float* out = (float*)d_out;

  // ws layout (offsets preserved from R5 for the fallback path):
  //   wbg    @ 0       : 384*6*8      = 18432 B
  //   bias2t @ 18432   : 32*384*4     = 49152 B
  //   bias2w @ 67584   : 384*32*4     = 49152 B
  //   Gg     @ 116736  : 64*32*6*32*8 = 3145728 B
  uint64_t* wbg = (uint64_t*)d_ws;
  float* bias2t = (float*)((char*)d_ws + 18432);
  float* bias2w = (float*)((char*)d_ws + 67584);
  uint64_t* Gg = (uint64_t*)((char*)d_ws + 116736);
  const size_t ws_need = 116736 + (size_t)BB * HH * 6 * WW * 8;  // 3262464

  const int use_split = (ws_size >= ws_need) ? 1 : 0;
  cyc_prep<<<IN_CH, 64, 0, stream>>>(wgt, bias, wbg, bias2t, bias2w, use_split);
  if (use_split) {
    cyc_pack<<<BB * (HH / HRA), 384, 0, stream>>>(x, Gg);
    cyc_gemm<<<BB * (HH / 2) * 2, 256, 0, stream>>>(Gg, wbg, bias2w, out);
  } else {
    cyc_main<<<BB * (HH / HR), 768, 0, stream>>>(x, wbg, bias2t, out);
  }
}